// Round 1
// baseline (66.031 us; speedup 1.0000x reference)
//
#include <hip/hip_runtime.h>

#define C_IN   256
#define C_OUT  128
#define H_DIM  270
#define W_DIM  480
#define N_PTS  512
#define K_CLS  5

// ---------------------------------------------------------------------------
// Kernel 0: transpose conv_w [co][ci][3][3] -> w_t [(ci*9+k)][co]
// so the conv kernel's 128-lane weight reads are coalesced.
// ---------------------------------------------------------------------------
__global__ void transpose_w(const float* __restrict__ conv_w,
                            float* __restrict__ w_t) {
    int idx = blockIdx.x * blockDim.x + threadIdx.x;   // 0 .. 294911
    if (idx >= C_OUT * C_IN * 9) return;
    int co  = idx / (C_IN * 9);
    int rem = idx % (C_IN * 9);                        // ci*9 + k
    w_t[rem * C_OUT + co] = conv_w[idx];
}

// ---------------------------------------------------------------------------
// Kernel 1: gather-conv. One block per sampled point.
// 256 threads = 128 output channels x 2 ci-halves.
// Patch (256 ci x 9 taps = 9.2 KB) staged in LDS; reads are broadcast.
// Weight reads: lanes 0..127 hit consecutive co -> fully coalesced, L2-hot.
// ---------------------------------------------------------------------------
__global__ __launch_bounds__(256) void gather_conv(
        const float* __restrict__ bb,       // [C_IN][H][W]
        const int*   __restrict__ centers,  // [N][2] (x, y)
        const float* __restrict__ w_t,      // [(ci*9+k)][co]
        const float* __restrict__ conv_b,   // [C_OUT]
        float*       __restrict__ vecs)     // [N][C_OUT]
{
    __shared__ float patch[C_IN * 9];
    __shared__ float red[256];

    const int n  = blockIdx.x;
    const int t  = threadIdx.x;
    const int cx = centers[2 * n];      // indexes W
    const int cy = centers[2 * n + 1];  // indexes H

    // --- stage patch: thread t loads the 9 taps of channel ci = t ---
    {
        const int ci = t;
        const float* base = bb + (size_t)ci * (H_DIM * W_DIM);
        #pragma unroll
        for (int dy = 0; dy < 3; ++dy) {
            int y = cy + dy - 1;
            #pragma unroll
            for (int dx = 0; dx < 3; ++dx) {
                int x = cx + dx - 1;
                float v = 0.f;
                if (y >= 0 && y < H_DIM && x >= 0 && x < W_DIM)
                    v = base[y * W_DIM + x];
                patch[ci * 9 + dy * 3 + dx] = v;   // 9 odd stride -> 2-way max, free
            }
        }
    }
    __syncthreads();

    // --- accumulate: co = t&127, ci-half = t>>7 ---
    const int co   = t & 127;
    const int half = t >> 7;
    const float* wp = w_t + co;
    float acc = 0.f;
    const int ci0 = half * 128;
    for (int ci = ci0; ci < ci0 + 128; ++ci) {
        #pragma unroll
        for (int k = 0; k < 9; ++k) {
            acc = fmaf(patch[ci * 9 + k], wp[(ci * 9 + k) * C_OUT], acc);
        }
    }
    red[t] = acc;
    __syncthreads();

    if (t < 128) {
        float s = red[t] + red[t + 128] + conv_b[co];
        vecs[n * C_OUT + co] = fmaxf(s, 0.f);       // fused bias + relu
    }
}

// ---------------------------------------------------------------------------
// Kernel 2: head. One wave (64 lanes) per point.
// logits = vecs @ fc_w^T + fc_b; softmax; P; per-point NLL partial.
// log(P) computed as (logit - m) - log(sum_exp) for accuracy.
// ---------------------------------------------------------------------------
__global__ __launch_bounds__(64) void head_kernel(
        const float* __restrict__ vecs,   // [N][C_OUT]
        const float* __restrict__ fc_w,   // [K][C_OUT]
        const float* __restrict__ fc_b,   // [K]
        const float* __restrict__ L,      // [N][K]
        float*       __restrict__ P,      // [N][K]
        float*       __restrict__ loss_part) // [N]
{
    const int n    = blockIdx.x;
    const int lane = threadIdx.x;

    const float v0 = vecs[n * C_OUT + lane];
    const float v1 = vecs[n * C_OUT + 64 + lane];

    float logit[K_CLS];
    #pragma unroll
    for (int k = 0; k < K_CLS; ++k) {
        float p = v0 * fc_w[k * C_OUT + lane] + v1 * fc_w[k * C_OUT + 64 + lane];
        #pragma unroll
        for (int off = 32; off > 0; off >>= 1)
            p += __shfl_xor(p, off, 64);
        logit[k] = p + fc_b[k];
    }

    if (lane == 0) {
        float m = logit[0];
        #pragma unroll
        for (int k = 1; k < K_CLS; ++k) m = fmaxf(m, logit[k]);
        float e[K_CLS];
        float s = 0.f;
        #pragma unroll
        for (int k = 0; k < K_CLS; ++k) { e[k] = expf(logit[k] - m); s += e[k]; }
        const float inv  = 1.f / s;
        const float logs = logf(s);
        float lp = 0.f;
        #pragma unroll
        for (int k = 0; k < K_CLS; ++k) {
            P[n * K_CLS + k] = e[k] * inv;
            lp -= L[n * K_CLS + k] * ((logit[k] - m) - logs);
        }
        loss_part[n] = lp;
    }
}

// ---------------------------------------------------------------------------
// Kernel 3: deterministic loss reduction (one block, no atomics).
// ---------------------------------------------------------------------------
__global__ __launch_bounds__(512) void reduce_loss(
        const float* __restrict__ loss_part, float* __restrict__ out) {
    __shared__ float sh[N_PTS];
    const int t = threadIdx.x;
    sh[t] = loss_part[t];
    __syncthreads();
    for (int s = N_PTS / 2; s > 0; s >>= 1) {
        if (t < s) sh[t] += sh[t + s];
        __syncthreads();
    }
    if (t == 0) out[0] = sh[0];
}

// ---------------------------------------------------------------------------
extern "C" void kernel_launch(void* const* d_in, const int* in_sizes, int n_in,
                              void* d_out, int out_size, void* d_ws, size_t ws_size,
                              hipStream_t stream) {
    const float* bb      = (const float*)d_in[0];   // backbone_map
    const int*   centers = (const int*)  d_in[1];
    const float* L       = (const float*)d_in[2];
    const float* conv_w  = (const float*)d_in[3];
    const float* conv_b  = (const float*)d_in[4];
    const float* fc_w    = (const float*)d_in[5];
    const float* fc_b    = (const float*)d_in[6];

    float* out = (float*)d_out;            // P: [0, 2560), loss: [2560]

    // workspace layout
    float* w_t       = (float*)d_ws;                   // 294912 floats
    float* vecs      = w_t + C_OUT * C_IN * 9;         //  65536 floats
    float* loss_part = vecs + N_PTS * C_OUT;           //    512 floats

    transpose_w<<<(C_OUT * C_IN * 9 + 255) / 256, 256, 0, stream>>>(conv_w, w_t);
    gather_conv<<<N_PTS, 256, 0, stream>>>(bb, centers, w_t, conv_b, vecs);
    head_kernel<<<N_PTS, 64, 0, stream>>>(vecs, fc_w, fc_b, L, out, loss_part);
    reduce_loss<<<1, N_PTS, 0, stream>>>(loss_part, out + N_PTS * K_CLS);
}

// Round 2
// 33.603 us; speedup vs baseline: 1.9650x; 1.9650x over previous
//
#include <hip/hip_runtime.h>

#define C_IN   256
#define C_OUT  128
#define H_DIM  270
#define W_DIM  480
#define N_PTS  512
#define K_CLS  5

#define PB     16                 // points per block
#define CC     16                 // K-chunks (ci split)
#define CI_PER (C_IN / CC)        // 16 ci per chunk
#define TERMS  (CI_PER * 9)       // 144 K-terms per chunk

// ---------------------------------------------------------------------------
// Kernel 0: transpose conv_w [co][ci][3][3] -> w_t [(ci*9+k)][co]
// so the conv kernel's weight reads are lane-coalesced.
// ---------------------------------------------------------------------------
__global__ __launch_bounds__(256) void transpose_w(
        const float* __restrict__ conv_w, float* __restrict__ w_t) {
    int idx = blockIdx.x * blockDim.x + threadIdx.x;   // 0 .. 294911
    if (idx >= C_OUT * C_IN * 9) return;
    int co  = idx / (C_IN * 9);
    int rem = idx % (C_IN * 9);                        // ci*9 + k
    w_t[rem * C_OUT + co] = conv_w[idx];
}

// ---------------------------------------------------------------------------
// Kernel 1: register-tiled gather-conv.
// Block = (chunk, point-group): 16 points x 144 K-terms -> partials.
// 256 threads = 64 co-pairs x 4 point-quarters; thread owns 2co x 4pts = 8 acc.
// Each float2 weight load feeds 8 FMAs; each broadcast b128 patch read feeds
// 8 FMAs. Partials[chunk][pt][co] summed later in the head kernel.
// ---------------------------------------------------------------------------
__global__ __launch_bounds__(256) void gather_conv(
        const float* __restrict__ bb,       // [C_IN][H][W]
        const int*   __restrict__ centers,  // [N][2] (x, y)
        const float* __restrict__ w_t,      // [(ci*9+k)][co]
        float*       __restrict__ part)     // [CC][N_PTS][C_OUT]
{
    __shared__ float patch[PB][TERMS];      // 16 * 144 * 4B = 9.2 KB

    const int chunk = blockIdx.x & (CC - 1);
    const int ptg   = blockIdx.x >> 4;      // 32 point groups
    const int t     = threadIdx.x;

    // --- stage: thread t handles (pt = t>>4, local ci = t&15) ---
    {
        const int pt  = t >> 4;
        const int lci = t & 15;
        const int ci  = chunk * CI_PER + lci;
        const int n   = ptg * PB + pt;
        const int cx  = centers[2 * n];     // indexes W
        const int cy  = centers[2 * n + 1]; // indexes H
        const float* base = bb + (size_t)ci * (H_DIM * W_DIM);
        #pragma unroll
        for (int dy = 0; dy < 3; ++dy) {
            int y = cy + dy - 1;
            #pragma unroll
            for (int dx = 0; dx < 3; ++dx) {
                int x = cx + dx - 1;
                float v = 0.f;
                if (y >= 0 && y < H_DIM && x >= 0 && x < W_DIM)
                    v = base[y * W_DIM + x];
                patch[pt][lci * 9 + dy * 3 + dx] = v;   // exactly 2 lanes/bank: free
            }
        }
    }
    __syncthreads();

    // --- compute: cp = co-pair (co = 2cp, 2cp+1), q = point quarter ---
    const int cp = t & 63;
    const int q  = t >> 6;          // whole wave shares q -> patch reads broadcast

    const float* wt_base = w_t + (size_t)(chunk * TERMS) * C_OUT + 2 * cp;

    float acc[4][2] = {{0.f,0.f},{0.f,0.f},{0.f,0.f},{0.f,0.f}};

    for (int g = 0; g < TERMS; g += 4) {
        const float2 w0 = *(const float2*)(wt_base + (size_t)(g + 0) * C_OUT);
        const float2 w1 = *(const float2*)(wt_base + (size_t)(g + 1) * C_OUT);
        const float2 w2 = *(const float2*)(wt_base + (size_t)(g + 2) * C_OUT);
        const float2 w3 = *(const float2*)(wt_base + (size_t)(g + 3) * C_OUT);
        #pragma unroll
        for (int p = 0; p < 4; ++p) {
            const float4 pv = *(const float4*)&patch[q * 4 + p][g];
            acc[p][0] = fmaf(pv.x, w0.x, acc[p][0]);
            acc[p][1] = fmaf(pv.x, w0.y, acc[p][1]);
            acc[p][0] = fmaf(pv.y, w1.x, acc[p][0]);
            acc[p][1] = fmaf(pv.y, w1.y, acc[p][1]);
            acc[p][0] = fmaf(pv.z, w2.x, acc[p][0]);
            acc[p][1] = fmaf(pv.z, w2.y, acc[p][1]);
            acc[p][0] = fmaf(pv.w, w3.x, acc[p][0]);
            acc[p][1] = fmaf(pv.w, w3.y, acc[p][1]);
        }
    }

    float* pout = part + ((size_t)chunk * N_PTS + ptg * PB) * C_OUT + 2 * cp;
    #pragma unroll
    for (int p = 0; p < 4; ++p) {
        *(float2*)(pout + (size_t)(q * 4 + p) * C_OUT) =
            make_float2(acc[p][0], acc[p][1]);
    }
}

// ---------------------------------------------------------------------------
// Kernel 2: head. One wave per point. Sums the CC partials (fixed order ->
// deterministic), fuses bias+relu, then logits / softmax / P / NLL partial.
// ---------------------------------------------------------------------------
__global__ __launch_bounds__(64) void head_kernel(
        const float* __restrict__ part,   // [CC][N_PTS][C_OUT]
        const float* __restrict__ conv_b, // [C_OUT]
        const float* __restrict__ fc_w,   // [K][C_OUT]
        const float* __restrict__ fc_b,   // [K]
        const float* __restrict__ L,      // [N][K]
        float*       __restrict__ P,      // [N][K]
        float*       __restrict__ loss_part) // [N]
{
    const int n    = blockIdx.x;
    const int lane = threadIdx.x;

    const float* pc = part + (size_t)n * C_OUT;
    float v0 = 0.f, v1 = 0.f;
    #pragma unroll
    for (int c = 0; c < CC; ++c) {
        v0 += pc[(size_t)c * N_PTS * C_OUT + lane];
        v1 += pc[(size_t)c * N_PTS * C_OUT + 64 + lane];
    }
    v0 = fmaxf(v0 + conv_b[lane], 0.f);
    v1 = fmaxf(v1 + conv_b[64 + lane], 0.f);

    float logit[K_CLS];
    #pragma unroll
    for (int k = 0; k < K_CLS; ++k) {
        float p = v0 * fc_w[k * C_OUT + lane] + v1 * fc_w[k * C_OUT + 64 + lane];
        #pragma unroll
        for (int off = 32; off > 0; off >>= 1)
            p += __shfl_xor(p, off, 64);
        logit[k] = p + fc_b[k];
    }

    if (lane == 0) {
        float m = logit[0];
        #pragma unroll
        for (int k = 1; k < K_CLS; ++k) m = fmaxf(m, logit[k]);
        float e[K_CLS];
        float s = 0.f;
        #pragma unroll
        for (int k = 0; k < K_CLS; ++k) { e[k] = expf(logit[k] - m); s += e[k]; }
        const float inv  = 1.f / s;
        const float logs = logf(s);
        float lp = 0.f;
        #pragma unroll
        for (int k = 0; k < K_CLS; ++k) {
            P[n * K_CLS + k] = e[k] * inv;
            lp -= L[n * K_CLS + k] * ((logit[k] - m) - logs);
        }
        loss_part[n] = lp;
    }
}

// ---------------------------------------------------------------------------
// Kernel 3: deterministic loss reduction (one block, no atomics).
// ---------------------------------------------------------------------------
__global__ __launch_bounds__(512) void reduce_loss(
        const float* __restrict__ loss_part, float* __restrict__ out) {
    __shared__ float sh[N_PTS];
    const int t = threadIdx.x;
    sh[t] = loss_part[t];
    __syncthreads();
    for (int s = N_PTS / 2; s > 0; s >>= 1) {
        if (t < s) sh[t] += sh[t + s];
        __syncthreads();
    }
    if (t == 0) out[0] = sh[0];
}

// ---------------------------------------------------------------------------
extern "C" void kernel_launch(void* const* d_in, const int* in_sizes, int n_in,
                              void* d_out, int out_size, void* d_ws, size_t ws_size,
                              hipStream_t stream) {
    const float* bb      = (const float*)d_in[0];   // backbone_map
    const int*   centers = (const int*)  d_in[1];
    const float* L       = (const float*)d_in[2];
    const float* conv_w  = (const float*)d_in[3];
    const float* conv_b  = (const float*)d_in[4];
    const float* fc_w    = (const float*)d_in[5];
    const float* fc_b    = (const float*)d_in[6];

    float* out = (float*)d_out;            // P: [0, 2560), loss: [2560]

    // workspace layout (floats)
    float* w_t       = (float*)d_ws;                        // 294912
    float* part      = w_t + C_OUT * C_IN * 9;              // 16*512*128 = 1048576
    float* loss_part = part + (size_t)CC * N_PTS * C_OUT;   // 512

    transpose_w<<<(C_OUT * C_IN * 9 + 255) / 256, 256, 0, stream>>>(conv_w, w_t);
    gather_conv<<<N_PTS / PB * CC, 256, 0, stream>>>(bb, centers, w_t, part);
    head_kernel<<<N_PTS, 64, 0, stream>>>(part, conv_b, fc_w, fc_b, L, out, loss_part);
    reduce_loss<<<1, N_PTS, 0, stream>>>(loss_part, out + N_PTS * K_CLS);
}